// Round 1
// 841.183 us; speedup vs baseline: 1.0423x; 1.0423x over previous
//
#include <hip/hip_runtime.h>
#include <hip/hip_bf16.h>

typedef unsigned short u16;
typedef __attribute__((ext_vector_type(8))) short s16x8;
typedef __attribute__((ext_vector_type(4))) float f32x4;

// fp32 -> bf16 round-to-nearest-even
__device__ __forceinline__ u16 f2bf(float f) {
    union { float f; unsigned u; } c; c.f = f;
    unsigned r = c.u + 0x7fffu + ((c.u >> 16) & 1u);
    return (u16)(r >> 16);
}

// async global->LDS, 16 bytes/lane. LDS dest is wave-uniform base + lane*16.
__device__ __forceinline__ void gld_lds16(const u16* g, u16* l) {
    __builtin_amdgcn_global_load_lds(
        (const __attribute__((address_space(1))) void*)g,
        (__attribute__((address_space(3))) void*)l, 16, 0, 0);
}

// ---------------- prep: row-sums of a; a->bf16 with +I folded into the diagonal -----------------
template<bool CVT>
__global__ __launch_bounds__(256) void rowsum_kernel(const float* __restrict__ a,
                                                     float* __restrict__ dsc,
                                                     u16* __restrict__ ab) {
    const int wave = threadIdx.x >> 6, lane = threadIdx.x & 63;
    const long row = (long)blockIdx.x * 4 + wave;   // 65536 rows, each 1024 floats
    const int diag = (int)(row & 1023);             // column index of the +I element
    const float4* a4 = (const float4*)(a + row * 1024);
    float s = 0.f;
    #pragma unroll
    for (int i = 0; i < 4; ++i) {
        float4 v = a4[i * 64 + lane];
        s += v.x + v.y + v.z + v.w;                 // raw rowsum (deg adds +1 below)
        if (CVT) {
            const int c0 = (i * 64 + lane) * 4;
            float e[4] = {v.x, v.y, v.z, v.w};
            if (diag >= c0 && diag < c0 + 4) e[diag - c0] += 1.0f;  // fold +I into bf16 A
            union { u16 u[4]; uint2 w; } cv;
            cv.u[0] = f2bf(e[0]); cv.u[1] = f2bf(e[1]);
            cv.u[2] = f2bf(e[2]); cv.u[3] = f2bf(e[3]);
            *(uint2*)(ab + row * 1024 + c0) = cv.w;
        }
    }
    #pragma unroll
    for (int off = 32; off > 0; off >>= 1) s += __shfl_down(s, off, 64);
    if (lane == 0) dsc[row] = rsqrtf(s + 1.0f + 1e-8f);
}

// ---------------- prep: xst[b][n][j] = bf16(d_j * x[b][j][n])  (transpose so GEMM1 B is [N,K]) ----
__global__ __launch_bounds__(256) void xst_kernel(const float* __restrict__ x,
                                                  const float* __restrict__ dsc,
                                                  u16* __restrict__ xst) {
    __shared__ u16 ls[64][65];
    const int b  = blockIdx.z;
    const int n0 = blockIdx.x * 64;   // over IN_DIM=512
    const int j0 = blockIdx.y * 64;   // over N=1024
    const int t  = threadIdx.x;
    {
        int jj = t >> 4, nn = (t & 15) * 4;
        #pragma unroll
        for (int it = 0; it < 4; ++it, jj += 16) {
            float dj = dsc[b * 1024 + j0 + jj];
            float4 v = *(const float4*)(x + ((long)(b * 1024 + j0 + jj)) * 512 + n0 + nn);
            ls[jj][nn + 0] = f2bf(v.x * dj);
            ls[jj][nn + 1] = f2bf(v.y * dj);
            ls[jj][nn + 2] = f2bf(v.z * dj);
            ls[jj][nn + 3] = f2bf(v.w * dj);
        }
    }
    __syncthreads();
    {
        int nn = t >> 2;
        int jv = (t & 3) * 8;
        #pragma unroll
        for (int it = 0; it < 2; ++it, jv += 32) {
            union { u16 u[8]; uint4 w; } cv;
            #pragma unroll
            for (int u = 0; u < 8; ++u) cv.u[u] = ls[jv + u][nn];
            *(uint4*)(xst + ((long)b * 512 + n0 + nn) * 1024 + j0 + jv) = cv.w;
        }
    }
}

// ---------------- prep: weights -> bf16; W_mu/W_lv concatenated into [512][1024] -----------------
__global__ __launch_bounds__(256) void cvt_weights(const float* __restrict__ W1,
                                                   const float* __restrict__ Wmu,
                                                   const float* __restrict__ Wlv,
                                                   u16* __restrict__ w1b,
                                                   u16* __restrict__ wml) {
    int i = blockIdx.x * 256 + threadIdx.x;          // 524288 = 1024*512 = 512*1024
    w1b[i] = f2bf(W1[i]);
    wml[i] = f2bf(i < 262144 ? Wmu[i] : Wlv[i - 262144]);
}

// ================= 256x256-tile phase-interleaved GEMM (T1+T2+T3/T4+T5) =========================
// C[m,n] = sum_k A[m,k]*Bt[n,k], bf16 inputs, BM=BN=256, BK=32, 8 waves (2Mx4N),
// per-wave 128x64 output (acc 8x4 f32x4 = 128 VGPR). LDS 64KB static: 2 dbuf x (A,B) x 256x32.
// Staging: global_load_lds width-16, linear LDS dest, XOR-swizzled GLOBAL source
// (col ^= (row&3)<<4 at 16B granules); ds_read uses the same swizzle -> conflict-free b128.
// Schedule per K-tile: [reads A(mi0-3)+B; bar; lgkm0; prio1; 16 MFMA; prio0; bar]
//                      [reads A(mi4-7);    bar; lgkm0; prio1; 16 MFMA; prio0; bar]
//                      [stage tile t+2 into just-freed buffer; s_waitcnt vmcnt(4); bar]
// vmcnt never drains to 0 in steady state (4 younger loads stay in flight across the barrier).
template<int EPI>
__global__ __launch_bounds__(512, 2) void gemm256(
    const u16* __restrict__ A, const u16* __restrict__ Bt,
    int K, long aBStride, long bBStride,
    const float* __restrict__ dsc,
    u16* __restrict__ outb,
    const float* __restrict__ bias0, const float* __restrict__ bias1,
    float* __restrict__ outMu, float* __restrict__ outLv)
{
    __shared__ __align__(16) u16 As[2][256 * 32];   // 2 x 16KB
    __shared__ __align__(16) u16 Bs[2][256 * 32];   // 2 x 16KB  (total exactly 64KB)

    // --- XCD-aware bijective block swizzle (all launches have nwg % 8 == 0) ---
    const int gx = gridDim.x, gy = gridDim.y;
    const int nwg = gx * gy * gridDim.z;
    const int fid = (blockIdx.z * gy + blockIdx.y) * gx + blockIdx.x;
    int swz = fid;
    if (!(nwg & 7)) swz = (fid & 7) * (nwg >> 3) + (fid >> 3);
    const int bx  = swz % gx;
    const int tmp = swz / gx;
    const int by  = tmp % gy;
    const int bz  = tmp / gy;

    const u16* Ab = A + (long)bz * aBStride;
    const u16* Bb = Bt + (long)bz * bBStride;
    const int n0 = bx * 256, m0 = by * 256;
    const int T = (int)threadIdx.x;
    const int wid = T >> 6, lane = T & 63, quad = lane >> 4, tr = lane & 15;
    const int wm = (wid >> 2) * 128;      // wave row-block (2)
    const int wn = (wid & 3) * 64;        // wave col-block (4)
    const int NT = K >> 5;                // K-tiles of 32

    // staging geometry: 512 threads cover one 128-row slot (8KB) per gld_lds; 2 slots/matrix.
    // LDS linear u16 index = slot*4096 + T*8  ->  row = slot*128 + T/4, colblk = T&3.
    // Source column is inverse-swizzled so that LDS(r, cblk) holds global (r, cblk^(r&3)).
    const int sr   = T >> 2;                          // 0..127
    const int scol = ((T & 3) ^ (sr & 3)) << 3;       // swizzled element col (0..24)
    const u16* gA = Ab + (long)(m0 + sr) * K + scol;
    const u16* gB = Bb + (long)(n0 + sr) * K + scol;
    const long rowK = (long)128 * K;                  // slot-1 row offset
    u16* const wA0 = &As[0][0] + wid * 512;           // wave-uniform LDS bases
    u16* const wB0 = &Bs[0][0] + wid * 512;
    u16* const wA1 = &As[1][0] + wid * 512;
    u16* const wB1 = &Bs[1][0] + wid * 512;

    f32x4 acc[8][4];
    #pragma unroll
    for (int i = 0; i < 8; ++i)
        #pragma unroll
        for (int j = 0; j < 4; ++j) acc[i][j] = (f32x4){0.f, 0.f, 0.f, 0.f};

    // prologue: stage K-tiles 0 and 1 (8 loads), wait the oldest 4 (tile 0), keep 4 in flight
    gld_lds16(gA,           wA0); gld_lds16(gA + rowK,        wA0 + 4096);
    gld_lds16(gB,           wB0); gld_lds16(gB + rowK,        wB0 + 4096);
    gld_lds16(gA + 32,      wA1); gld_lds16(gA + 32 + rowK,   wA1 + 4096);
    gld_lds16(gB + 32,      wB1); gld_lds16(gB + 32 + rowK,   wB1 + 4096);
    asm volatile("s_waitcnt vmcnt(4)" ::: "memory");
    __builtin_amdgcn_s_barrier();
    __builtin_amdgcn_sched_barrier(0);

    const u16* rdA  = &As[0][0]; const u16* rdB  = &Bs[0][0];
    const u16* rdA2 = &As[1][0]; const u16* rdB2 = &Bs[1][0];
    u16* stA = wA0; u16* stB = wB0;
    u16* stA2 = wA1; u16* stB2 = wB1;

    const int rofs = (quad ^ (tr & 3)) << 3;      // swizzled ds_read col (u16 units)
    const int rbA  = (wm + tr) * 32 + rofs;

    for (int t = 0; t < NT; ++t) {
        s16x8 af[4], bfv[4];
        // ---- phase 0: read A(mi 0-3) + all B; MFMA upper half ----
        #pragma unroll
        for (int i = 0; i < 4; ++i) af[i]  = *(const s16x8*)&rdA[rbA + i * 512];
        #pragma unroll
        for (int i = 0; i < 4; ++i) bfv[i] = *(const s16x8*)&rdB[(wn + i * 16 + tr) * 32 + rofs];
        __builtin_amdgcn_s_barrier();
        asm volatile("s_waitcnt lgkmcnt(0)" ::: "memory");
        __builtin_amdgcn_sched_barrier(0);
        __builtin_amdgcn_s_setprio(1);
        #pragma unroll
        for (int mi = 0; mi < 4; ++mi)
            #pragma unroll
            for (int ni = 0; ni < 4; ++ni)
                acc[mi][ni] = __builtin_amdgcn_mfma_f32_16x16x32_bf16(af[mi], bfv[ni], acc[mi][ni], 0, 0, 0);
        __builtin_amdgcn_s_setprio(0);
        __builtin_amdgcn_s_barrier();
        // ---- phase 1: read A(mi 4-7); MFMA lower half ----
        #pragma unroll
        for (int i = 0; i < 4; ++i) af[i] = *(const s16x8*)&rdA[rbA + 2048 + i * 512];
        __builtin_amdgcn_s_barrier();
        asm volatile("s_waitcnt lgkmcnt(0)" ::: "memory");
        __builtin_amdgcn_sched_barrier(0);
        __builtin_amdgcn_s_setprio(1);
        #pragma unroll
        for (int mi = 0; mi < 4; ++mi)
            #pragma unroll
            for (int ni = 0; ni < 4; ++ni)
                acc[mi + 4][ni] = __builtin_amdgcn_mfma_f32_16x16x32_bf16(af[mi], bfv[ni], acc[mi + 4][ni], 0, 0, 0);
        __builtin_amdgcn_s_setprio(0);
        __builtin_amdgcn_s_barrier();      // all waves done reading this buffer
        __builtin_amdgcn_sched_barrier(0);
        // ---- boundary: stage tile t+2 into the just-freed buffer; counted wait ----
        if (t + 2 < NT) {
            const u16* a = gA + (long)(t + 2) * 32;
            const u16* b = gB + (long)(t + 2) * 32;
            gld_lds16(a, stA); gld_lds16(a + rowK, stA + 4096);
            gld_lds16(b, stB); gld_lds16(b + rowK, stB + 4096);
            asm volatile("s_waitcnt vmcnt(4)" ::: "memory");   // tile t+1 landed; t+2 in flight
        } else if (t + 1 < NT) {
            asm volatile("s_waitcnt vmcnt(0)" ::: "memory");   // tail drain
        }
        __builtin_amdgcn_s_barrier();
        __builtin_amdgcn_sched_barrier(0);
        // swap buffers
        const u16* tA = rdA; rdA = rdA2; rdA2 = tA;
        const u16* tB = rdB; rdB = rdB2; rdB2 = tB;
        u16* sA = stA; stA = stA2; stA2 = sA;
        u16* sB = stB; stB = stB2; stB2 = sB;
    }

    // ---- epilogue: C/D layout col=lane&15, row=quad*4+reg (m89-verified) ----
    if constexpr (EPI == 1) {
        #pragma unroll
        for (int mi = 0; mi < 8; ++mi) {
            const int gmB = m0 + wm + mi * 16 + quad * 4;
            #pragma unroll
            for (int r = 0; r < 4; ++r) {
                const long row = (long)bz * 1024 + gmB + r;
                const float d = dsc[row];
                #pragma unroll
                for (int ni = 0; ni < 4; ++ni) {
                    const int gn = n0 + wn + ni * 16 + tr;
                    outb[row * 512 + gn] = f2bf(d * acc[mi][ni][r]);
                }
            }
        }
    } else if constexpr (EPI == 2) {
        float bb[4];
        #pragma unroll
        for (int ni = 0; ni < 4; ++ni) bb[ni] = bias0[n0 + wn + ni * 16 + tr];
        #pragma unroll
        for (int mi = 0; mi < 8; ++mi) {
            const long gmB = m0 + wm + mi * 16 + quad * 4;
            #pragma unroll
            for (int ni = 0; ni < 4; ++ni) {
                const int gn = n0 + wn + ni * 16 + tr;
                #pragma unroll
                for (int r = 0; r < 4; ++r) {
                    float hv = acc[mi][ni][r] + bb[ni];
                    outb[(gmB + r) * 1024 + gn] = f2bf(hv > 0.f ? hv : 0.f);
                }
            }
        }
    } else {
        // n0 in {0,256}: entire block is mu or lv
        float* op       = (n0 == 0) ? outMu : outLv;
        const float* bp = (n0 == 0) ? bias0 : bias1;
        float bb[4];
        #pragma unroll
        for (int ni = 0; ni < 4; ++ni) bb[ni] = bp[wn + ni * 16 + tr];
        #pragma unroll
        for (int mi = 0; mi < 8; ++mi) {
            const long gmB = m0 + wm + mi * 16 + quad * 4;
            #pragma unroll
            for (int ni = 0; ni < 4; ++ni) {
                const int cn = wn + ni * 16 + tr;
                #pragma unroll
                for (int r = 0; r < 4; ++r)
                    op[(gmB + r) * 256 + cn] = acc[mi][ni][r] + bb[ni];
            }
        }
    }
}

// ---------------- fallback GEMM1 (fp32 A inline-converted) if ws can't hold bf16 a ---------------
__global__ __launch_bounds__(256) void gemm_f32a(
    const float* __restrict__ A, const u16* __restrict__ Bt,
    const float* __restrict__ dsc, const float* __restrict__ xin,
    u16* __restrict__ outb)
{
    __shared__ __align__(16) u16 As[128 * 40];
    __shared__ __align__(16) u16 Bs[128 * 40];
    const int bz = blockIdx.z;
    const float* Ab = A + (long)bz * 1024 * 1024;
    const u16* Bb = Bt + (long)bz * 512 * 1024;
    const int n0 = blockIdx.x * 128, m0 = blockIdx.y * 128;
    const int t = threadIdx.x;
    const int wave = t >> 6, lane = t & 63, quad = lane >> 4, tr = lane & 15;
    const int wm = (wave >> 1) * 64, wn = (wave & 1) * 64;
    const int K = 1024;

    f32x4 acc[4][4];
    #pragma unroll
    for (int i = 0; i < 4; ++i)
        #pragma unroll
        for (int j = 0; j < 4; ++j) acc[i][j] = (f32x4){0.f, 0.f, 0.f, 0.f};

    const int mm = t >> 2, kk = (t & 3) * 8;
    for (int k0 = 0; k0 < K; k0 += 32) {
        #pragma unroll
        for (int it = 0; it < 2; ++it) {
            const int r = mm + it * 64;
            const float4* p = (const float4*)(Ab + (long)(m0 + r) * K + k0 + kk);
            float4 v0 = p[0], v1 = p[1];
            union { u16 u[8]; uint4 w; } cv;
            cv.u[0]=f2bf(v0.x); cv.u[1]=f2bf(v0.y); cv.u[2]=f2bf(v0.z); cv.u[3]=f2bf(v0.w);
            cv.u[4]=f2bf(v1.x); cv.u[5]=f2bf(v1.y); cv.u[6]=f2bf(v1.z); cv.u[7]=f2bf(v1.w);
            *(uint4*)&As[r * 40 + kk] = cv.w;
            uint4 v = *(const uint4*)(Bb + (long)(n0 + r) * K + k0 + kk);
            *(uint4*)&Bs[r * 40 + kk] = v;
        }
        __syncthreads();
        s16x8 af[4], bfv[4];
        #pragma unroll
        for (int mi = 0; mi < 4; ++mi)
            af[mi] = *(const s16x8*)&As[(wm + mi * 16 + tr) * 40 + quad * 8];
        #pragma unroll
        for (int ni = 0; ni < 4; ++ni)
            bfv[ni] = *(const s16x8*)&Bs[(wn + ni * 16 + tr) * 40 + quad * 8];
        #pragma unroll
        for (int mi = 0; mi < 4; ++mi)
            #pragma unroll
            for (int ni = 0; ni < 4; ++ni)
                acc[mi][ni] = __builtin_amdgcn_mfma_f32_16x16x32_bf16(af[mi], bfv[ni], acc[mi][ni], 0, 0, 0);
        __syncthreads();
    }
    #pragma unroll
    for (int mi = 0; mi < 4; ++mi)
        #pragma unroll
        for (int ni = 0; ni < 4; ++ni) {
            const int gn = n0 + wn + ni * 16 + tr;
            #pragma unroll
            for (int r = 0; r < 4; ++r) {
                const int gm = m0 + wm + mi * 16 + quad * 4 + r;
                long row = (long)bz * 1024 + gm;
                float di = dsc[row];
                outb[row * 512 + gn] = f2bf(di * (acc[mi][ni][r] + di * xin[row * 512 + gn]));
            }
        }
}

extern "C" void kernel_launch(void* const* d_in, const int* in_sizes, int n_in,
                              void* d_out, int out_size, void* d_ws, size_t ws_size,
                              hipStream_t stream) {
    const float* x   = (const float*)d_in[0];   // [64,1024,512]
    const float* a   = (const float*)d_in[1];   // [64,1024,1024]
    const float* W1  = (const float*)d_in[2];   // [1024,512]
    const float* b1  = (const float*)d_in[3];   // [1024]
    const float* Wmu = (const float*)d_in[4];   // [256,1024]
    const float* bmu = (const float*)d_in[5];   // [256]
    const float* Wlv = (const float*)d_in[6];   // [256,1024]
    const float* blv = (const float*)d_in[7];   // [256]
    float* out = (float*)d_out;                 // mu [64,1024,256] then logvar [64,1024,256]

    char* base = (char*)d_ws;
    size_t off = 0;
    auto take = [&](size_t bytes) { char* p = base + off; off += (bytes + 255) & ~(size_t)255; return p; };
    float* dsc = (float*)take((size_t)65536 * 4);              // D^-1/2 per (b,i)
    u16*  xst  = (u16*)take((size_t)64 * 512 * 1024 * 2);      // [b][n][j] bf16
    u16*  h    = (u16*)take((size_t)65536 * 512 * 2);          // GEMM1 out
    u16*  hid  = (u16*)take((size_t)65536 * 1024 * 2);         // GEMM2 out
    u16*  w1b  = (u16*)take((size_t)1024 * 512 * 2);
    u16*  wml  = (u16*)take((size_t)512 * 1024 * 2);
    u16*  ab   = (u16*)take((size_t)64 * 1024 * 1024 * 2);     // bf16 copy of (a + I)
    const bool useAb = (off <= ws_size);

    if (useAb) rowsum_kernel<true ><<<16384, 256, 0, stream>>>(a, dsc, ab);
    else       rowsum_kernel<false><<<16384, 256, 0, stream>>>(a, dsc, nullptr);
    xst_kernel<<<dim3(8, 16, 64), 256, 0, stream>>>(x, dsc, xst);
    cvt_weights<<<2048, 256, 0, stream>>>(W1, Wmu, Wlv, w1b, wml);

    if (useAb)
        gemm256<1><<<dim3(2, 4, 64), 512, 0, stream>>>(
            ab, xst, 1024, 1024L * 1024, 512L * 1024,
            dsc, h, nullptr, nullptr, nullptr, nullptr);
    else
        gemm_f32a<<<dim3(4, 8, 64), 256, 0, stream>>>(a, xst, dsc, x, h);

    gemm256<2><<<dim3(4, 256, 1), 512, 0, stream>>>(
        h, w1b, 512, 0, 0, nullptr, hid, b1, nullptr, nullptr, nullptr);

    gemm256<3><<<dim3(2, 256, 1), 512, 0, stream>>>(
        hid, wml, 1024, 0, 0, nullptr, nullptr, bmu, blv,
        out, out + (size_t)65536 * 256);
}

// Round 3
// 768.062 us; speedup vs baseline: 1.1415x; 1.0952x over previous
//
#include <hip/hip_runtime.h>
#include <hip/hip_bf16.h>

typedef unsigned short u16;
typedef __attribute__((ext_vector_type(8))) short s16x8;
typedef __attribute__((ext_vector_type(4))) float f32x4;

// fp32 -> bf16 round-to-nearest-even
__device__ __forceinline__ u16 f2bf(float f) {
    union { float f; unsigned u; } c; c.f = f;
    unsigned r = c.u + 0x7fffu + ((c.u >> 16) & 1u);
    return (u16)(r >> 16);
}

// async global->LDS, 16 bytes/lane. LDS dest is wave-uniform base + lane*16.
__device__ __forceinline__ void gld_lds16(const u16* g, u16* l) {
    __builtin_amdgcn_global_load_lds(
        (const __attribute__((address_space(1))) void*)g,
        (__attribute__((address_space(3))) void*)l, 16, 0, 0);
}

// ---------------- prep: row-sums of a; a->bf16 with +I folded into the diagonal -----------------
template<bool CVT>
__global__ __launch_bounds__(256) void rowsum_kernel(const float* __restrict__ a,
                                                     float* __restrict__ dsc,
                                                     u16* __restrict__ ab) {
    const int wave = threadIdx.x >> 6, lane = threadIdx.x & 63;
    const long row = (long)blockIdx.x * 4 + wave;   // 65536 rows, each 1024 floats
    const int diag = (int)(row & 1023);             // column index of the +I element
    const float4* a4 = (const float4*)(a + row * 1024);
    float s = 0.f;
    #pragma unroll
    for (int i = 0; i < 4; ++i) {
        float4 v = a4[i * 64 + lane];
        s += v.x + v.y + v.z + v.w;                 // raw rowsum (deg adds +1 below)
        if (CVT) {
            const int c0 = (i * 64 + lane) * 4;
            float e[4] = {v.x, v.y, v.z, v.w};
            if (diag >= c0 && diag < c0 + 4) e[diag - c0] += 1.0f;  // fold +I into bf16 A
            union { u16 u[4]; uint2 w; } cv;
            cv.u[0] = f2bf(e[0]); cv.u[1] = f2bf(e[1]);
            cv.u[2] = f2bf(e[2]); cv.u[3] = f2bf(e[3]);
            *(uint2*)(ab + row * 1024 + c0) = cv.w;
        }
    }
    #pragma unroll
    for (int off = 32; off > 0; off >>= 1) s += __shfl_down(s, off, 64);
    if (lane == 0) dsc[row] = rsqrtf(s + 1.0f + 1e-8f);
}

// ---------------- prep: xst[b][n][j] = bf16(d_j * x[b][j][n])  (transpose so GEMM1 B is [N,K]) ----
__global__ __launch_bounds__(256) void xst_kernel(const float* __restrict__ x,
                                                  const float* __restrict__ dsc,
                                                  u16* __restrict__ xst) {
    __shared__ u16 ls[64][65];
    const int b  = blockIdx.z;
    const int n0 = blockIdx.x * 64;   // over IN_DIM=512
    const int j0 = blockIdx.y * 64;   // over N=1024
    const int t  = threadIdx.x;
    {
        int jj = t >> 4, nn = (t & 15) * 4;
        #pragma unroll
        for (int it = 0; it < 4; ++it, jj += 16) {
            float dj = dsc[b * 1024 + j0 + jj];
            float4 v = *(const float4*)(x + ((long)(b * 1024 + j0 + jj)) * 512 + n0 + nn);
            ls[jj][nn + 0] = f2bf(v.x * dj);
            ls[jj][nn + 1] = f2bf(v.y * dj);
            ls[jj][nn + 2] = f2bf(v.z * dj);
            ls[jj][nn + 3] = f2bf(v.w * dj);
        }
    }
    __syncthreads();
    {
        int nn = t >> 2;
        int jv = (t & 3) * 8;
        #pragma unroll
        for (int it = 0; it < 2; ++it, jv += 32) {
            union { u16 u[8]; uint4 w; } cv;
            #pragma unroll
            for (int u = 0; u < 8; ++u) cv.u[u] = ls[jv + u][nn];
            *(uint4*)(xst + ((long)b * 512 + n0 + nn) * 1024 + j0 + jv) = cv.w;
        }
    }
}

// ---------------- prep: weights -> bf16; W_mu/W_lv concatenated into [512][1024] -----------------
__global__ __launch_bounds__(256) void cvt_weights(const float* __restrict__ W1,
                                                   const float* __restrict__ Wmu,
                                                   const float* __restrict__ Wlv,
                                                   u16* __restrict__ w1b,
                                                   u16* __restrict__ wml) {
    int i = blockIdx.x * 256 + threadIdx.x;          // 524288 = 1024*512 = 512*1024
    w1b[i] = f2bf(W1[i]);
    wml[i] = f2bf(i < 262144 ? Wmu[i] : Wlv[i - 262144]);
}

// ================= 256x256-tile GEMM, 4-deep ring (prefetch distance 3), dynamic LDS ============
// C[m,n] = sum_k A[m,k]*Bt[n,k], bf16, BM=BN=256, BK=32, 8 waves (2Mx4N), per-wave 128x64 out.
// LDS 128KB dynamic: 4 ring slots x (A 16KB + B 16KB). Staging: global_load_lds width-16,
// linear LDS dest, source chunk pre-swizzled c ^= (row>>1)&3 (16B granules); ds_read applies the
// same XOR -> lanes 0..15 of a b128 hit 8 distinct banks (2-way aliasing = free, m136).
// Per K-tile: [read af0,bfv (8xb128); bar; 16 MFMA; bar;
//              read af1 (4xb128); STAGE t+3; vmcnt(8); bar; 16 MFMA; bar]
// vmcnt(8) => tile t+1 landed, t+2/t+3 in flight (distance-3 cover of ~900cy HBM latency).
template<int EPI>
__global__ __launch_bounds__(512, 2) void gemm256(
    const u16* __restrict__ A, const u16* __restrict__ Bt,
    int K, long aBStride, long bBStride,
    const float* __restrict__ dsc,
    u16* __restrict__ outb,
    const float* __restrict__ bias0, const float* __restrict__ bias1,
    float* __restrict__ outMu, float* __restrict__ outLv)
{
    extern __shared__ __align__(16) u16 smem[];   // 128KB: As 4x8192 u16, Bs 4x8192 u16
    u16* const Asl = smem;
    u16* const Bsl = smem + 4 * 8192;

    // --- XCD-aware bijective block swizzle (all launches have nwg % 8 == 0) ---
    const int gx = gridDim.x, gy = gridDim.y;
    const int nwg = gx * gy * gridDim.z;
    const int fid = (blockIdx.z * gy + blockIdx.y) * gx + blockIdx.x;
    int swz = fid;
    if (!(nwg & 7)) swz = (fid & 7) * (nwg >> 3) + (fid >> 3);
    const int bx  = swz % gx;
    const int tmp = swz / gx;
    const int by  = tmp % gy;
    const int bz  = tmp / gy;

    const u16* Ab = A + (long)bz * aBStride;
    const u16* Bb = Bt + (long)bz * bBStride;
    const int n0 = bx * 256, m0 = by * 256;
    const int T = (int)threadIdx.x;
    const int wid = T >> 6, lane = T & 63, quad = lane >> 4, tr = lane & 15;
    const int wm = (wid >> 2) * 128;      // wave row-block (2)
    const int wn = (wid & 3) * 64;        // wave col-block (4)
    const int NT = K >> 5;                // K-tiles of 32

    // staging: thread T -> row T/4 (0..127) per 128-row slot-half, 16B chunk T&3.
    // source chunk inverse-swizzled so LDS(r,c) = global(r, c ^ ((r>>1)&3)).
    const int sr   = T >> 2;
    const int scol = ((T & 3) ^ ((sr >> 1) & 3)) << 3;   // u16 units
    const u16* gA = Ab + (long)(m0 + sr) * K + scol;
    const u16* gB = Bb + (long)(n0 + sr) * K + scol;
    const long rowK = (long)128 * K;
    const int wofs = wid * 512;                          // wave-uniform LDS chunk (u16)

    f32x4 acc[8][4];
    #pragma unroll
    for (int i = 0; i < 8; ++i)
        #pragma unroll
        for (int j = 0; j < 4; ++j) acc[i][j] = (f32x4){0.f, 0.f, 0.f, 0.f};

    // read-side: global chunk 'quad' of row r lives at LDS chunk quad ^ ((r>>1)&3)
    const int rofs = (quad ^ ((tr >> 1) & 3)) << 3;      // u16 units
    const int rbA  = (wm + tr) * 32 + rofs;
    const int rbB  = (wn + tr) * 32 + rofs;

    #define STAGE(slot, t) do {                                         \
        const u16* ga_ = gA + (long)(t) * 32;                           \
        const u16* gb_ = gB + (long)(t) * 32;                           \
        u16* la_ = Asl + (slot) * 8192 + wofs;                          \
        u16* lb_ = Bsl + (slot) * 8192 + wofs;                          \
        gld_lds16(ga_, la_); gld_lds16(ga_ + rowK, la_ + 4096);         \
        gld_lds16(gb_, lb_); gld_lds16(gb_ + rowK, lb_ + 4096);         \
    } while (0)

    // prologue: stage tiles 0,1,2 (12 loads); wait oldest 4 (tile 0); 8 stay in flight
    STAGE(0, 0); STAGE(1, 1); STAGE(2, 2);
    asm volatile("s_waitcnt vmcnt(8)" ::: "memory");
    __builtin_amdgcn_s_barrier();
    __builtin_amdgcn_sched_barrier(0);

    for (int t = 0; t < NT; ++t) {
        const u16* rdA = Asl + (t & 3) * 8192;
        const u16* rdB = Bsl + (t & 3) * 8192;
        s16x8 af0[4], bfv[4], af1[4];
        // ---- region 0: fragment reads for phase 0 ----
        #pragma unroll
        for (int i = 0; i < 4; ++i) af0[i] = *(const s16x8*)&rdA[rbA + i * 512];
        #pragma unroll
        for (int i = 0; i < 4; ++i) bfv[i] = *(const s16x8*)&rdB[rbB + i * 512];
        __builtin_amdgcn_s_barrier();
        __builtin_amdgcn_sched_barrier(0);
        // ---- phase 0: MFMA upper half (compiler inserts counted lgkm waits) ----
        __builtin_amdgcn_s_setprio(1);
        #pragma unroll
        for (int mi = 0; mi < 4; ++mi)
            #pragma unroll
            for (int ni = 0; ni < 4; ++ni)
                acc[mi][ni] = __builtin_amdgcn_mfma_f32_16x16x32_bf16(af0[mi], bfv[ni], acc[mi][ni], 0, 0, 0);
        __builtin_amdgcn_s_setprio(0);
        __builtin_amdgcn_s_barrier();
        __builtin_amdgcn_sched_barrier(0);
        // ---- region 1: phase-1 A reads, stage tile t+3, counted vmcnt ----
        #pragma unroll
        for (int i = 0; i < 4; ++i) af1[i] = *(const s16x8*)&rdA[rbA + 2048 + i * 512];
        if (t + 3 < NT) {
            STAGE((t + 3) & 3, t + 3);
            asm volatile("s_waitcnt vmcnt(8)" ::: "memory");   // t+1 landed; t+2,t+3 in flight
        } else if (t + 2 < NT) {
            asm volatile("s_waitcnt vmcnt(4)" ::: "memory");   // t+1 landed; t+2 in flight
        } else if (t + 1 < NT) {
            asm volatile("s_waitcnt vmcnt(0)" ::: "memory");   // tail drain
        }
        __builtin_amdgcn_s_barrier();                          // all waves' t+1 data visible
        __builtin_amdgcn_sched_barrier(0);
        // ---- phase 1: MFMA lower half ----
        __builtin_amdgcn_s_setprio(1);
        #pragma unroll
        for (int mi = 0; mi < 4; ++mi)
            #pragma unroll
            for (int ni = 0; ni < 4; ++ni)
                acc[mi + 4][ni] = __builtin_amdgcn_mfma_f32_16x16x32_bf16(af1[mi], bfv[ni], acc[mi + 4][ni], 0, 0, 0);
        __builtin_amdgcn_s_setprio(0);
        __builtin_amdgcn_s_barrier();                          // slot t%4 free for reuse
        __builtin_amdgcn_sched_barrier(0);
    }
    #undef STAGE

    // ---- epilogue: C/D layout col=lane&15, row=quad*4+reg (m89-verified) ----
    if constexpr (EPI == 1) {
        #pragma unroll
        for (int mi = 0; mi < 8; ++mi) {
            const int gmB = m0 + wm + mi * 16 + quad * 4;
            #pragma unroll
            for (int r = 0; r < 4; ++r) {
                const long row = (long)bz * 1024 + gmB + r;
                const float d = dsc[row];
                #pragma unroll
                for (int ni = 0; ni < 4; ++ni) {
                    const int gn = n0 + wn + ni * 16 + tr;
                    outb[row * 512 + gn] = f2bf(d * acc[mi][ni][r]);
                }
            }
        }
    } else if constexpr (EPI == 2) {
        float bb[4];
        #pragma unroll
        for (int ni = 0; ni < 4; ++ni) bb[ni] = bias0[n0 + wn + ni * 16 + tr];
        #pragma unroll
        for (int mi = 0; mi < 8; ++mi) {
            const long gmB = m0 + wm + mi * 16 + quad * 4;
            #pragma unroll
            for (int ni = 0; ni < 4; ++ni) {
                const int gn = n0 + wn + ni * 16 + tr;
                #pragma unroll
                for (int r = 0; r < 4; ++r) {
                    float hv = acc[mi][ni][r] + bb[ni];
                    outb[(gmB + r) * 1024 + gn] = f2bf(hv > 0.f ? hv : 0.f);
                }
            }
        }
    } else {
        // n0 in {0,256}: entire block is mu or lv
        float* op       = (n0 == 0) ? outMu : outLv;
        const float* bp = (n0 == 0) ? bias0 : bias1;
        float bb[4];
        #pragma unroll
        for (int ni = 0; ni < 4; ++ni) bb[ni] = bp[wn + ni * 16 + tr];
        #pragma unroll
        for (int mi = 0; mi < 8; ++mi) {
            const long gmB = m0 + wm + mi * 16 + quad * 4;
            #pragma unroll
            for (int ni = 0; ni < 4; ++ni) {
                const int cn = wn + ni * 16 + tr;
                #pragma unroll
                for (int r = 0; r < 4; ++r)
                    op[(gmB + r) * 256 + cn] = acc[mi][ni][r] + bb[ni];
            }
        }
    }
}

// ---------------- fallback GEMM1 (fp32 A inline-converted) if ws can't hold bf16 a ---------------
__global__ __launch_bounds__(256) void gemm_f32a(
    const float* __restrict__ A, const u16* __restrict__ Bt,
    const float* __restrict__ dsc, const float* __restrict__ xin,
    u16* __restrict__ outb)
{
    __shared__ __align__(16) u16 As[128 * 40];
    __shared__ __align__(16) u16 Bs[128 * 40];
    const int bz = blockIdx.z;
    const float* Ab = A + (long)bz * 1024 * 1024;
    const u16* Bb = Bt + (long)bz * 512 * 1024;
    const int n0 = blockIdx.x * 128, m0 = blockIdx.y * 128;
    const int t = threadIdx.x;
    const int wave = t >> 6, lane = t & 63, quad = lane >> 4, tr = lane & 15;
    const int wm = (wave >> 1) * 64, wn = (wave & 1) * 64;
    const int K = 1024;

    f32x4 acc[4][4];
    #pragma unroll
    for (int i = 0; i < 4; ++i)
        #pragma unroll
        for (int j = 0; j < 4; ++j) acc[i][j] = (f32x4){0.f, 0.f, 0.f, 0.f};

    const int mm = t >> 2, kk = (t & 3) * 8;
    for (int k0 = 0; k0 < K; k0 += 32) {
        #pragma unroll
        for (int it = 0; it < 2; ++it) {
            const int r = mm + it * 64;
            const float4* p = (const float4*)(Ab + (long)(m0 + r) * K + k0 + kk);
            float4 v0 = p[0], v1 = p[1];
            union { u16 u[8]; uint4 w; } cv;
            cv.u[0]=f2bf(v0.x); cv.u[1]=f2bf(v0.y); cv.u[2]=f2bf(v0.z); cv.u[3]=f2bf(v0.w);
            cv.u[4]=f2bf(v1.x); cv.u[5]=f2bf(v1.y); cv.u[6]=f2bf(v1.z); cv.u[7]=f2bf(v1.w);
            *(uint4*)&As[r * 40 + kk] = cv.w;
            uint4 v = *(const uint4*)(Bb + (long)(n0 + r) * K + k0 + kk);
            *(uint4*)&Bs[r * 40 + kk] = v;
        }
        __syncthreads();
        s16x8 af[4], bfv[4];
        #pragma unroll
        for (int mi = 0; mi < 4; ++mi)
            af[mi] = *(const s16x8*)&As[(wm + mi * 16 + tr) * 40 + quad * 8];
        #pragma unroll
        for (int ni = 0; ni < 4; ++ni)
            bfv[ni] = *(const s16x8*)&Bs[(wn + ni * 16 + tr) * 40 + quad * 8];
        #pragma unroll
        for (int mi = 0; mi < 4; ++mi)
            #pragma unroll
            for (int ni = 0; ni < 4; ++ni)
                acc[mi][ni] = __builtin_amdgcn_mfma_f32_16x16x32_bf16(af[mi], bfv[ni], acc[mi][ni], 0, 0, 0);
        __syncthreads();
    }
    #pragma unroll
    for (int mi = 0; mi < 4; ++mi)
        #pragma unroll
        for (int ni = 0; ni < 4; ++ni) {
            const int gn = n0 + wn + ni * 16 + tr;
            #pragma unroll
            for (int r = 0; r < 4; ++r) {
                const int gm = m0 + wm + mi * 16 + quad * 4 + r;
                long row = (long)bz * 1024 + gm;
                float di = dsc[row];
                outb[row * 512 + gn] = f2bf(di * (acc[mi][ni][r] + di * xin[row * 512 + gn]));
            }
        }
}

extern "C" void kernel_launch(void* const* d_in, const int* in_sizes, int n_in,
                              void* d_out, int out_size, void* d_ws, size_t ws_size,
                              hipStream_t stream) {
    const float* x   = (const float*)d_in[0];   // [64,1024,512]
    const float* a   = (const float*)d_in[1];   // [64,1024,1024]
    const float* W1  = (const float*)d_in[2];   // [1024,512]
    const float* b1  = (const float*)d_in[3];   // [1024]
    const float* Wmu = (const float*)d_in[4];   // [256,1024]
    const float* bmu = (const float*)d_in[5];   // [256]
    const float* Wlv = (const float*)d_in[6];   // [256,1024]
    const float* blv = (const float*)d_in[7];   // [256]
    float* out = (float*)d_out;                 // mu [64,1024,256] then logvar [64,1024,256]

    // one-time: allow 128KB dynamic LDS on the gemm kernels (host-side, capture-safe; ignore rc)
    static bool attrDone = false;
    if (!attrDone) {
        (void)hipFuncSetAttribute((const void*)gemm256<1>, hipFuncAttributeMaxDynamicSharedMemorySize, 131072);
        (void)hipFuncSetAttribute((const void*)gemm256<2>, hipFuncAttributeMaxDynamicSharedMemorySize, 131072);
        (void)hipFuncSetAttribute((const void*)gemm256<3>, hipFuncAttributeMaxDynamicSharedMemorySize, 131072);
        attrDone = true;
    }

    char* base = (char*)d_ws;
    size_t off = 0;
    auto take = [&](size_t bytes) { char* p = base + off; off += (bytes + 255) & ~(size_t)255; return p; };
    float* dsc = (float*)take((size_t)65536 * 4);              // D^-1/2 per (b,i)
    u16*  xst  = (u16*)take((size_t)64 * 512 * 1024 * 2);      // [b][n][j] bf16
    u16*  h    = (u16*)take((size_t)65536 * 512 * 2);          // GEMM1 out
    u16*  hid  = (u16*)take((size_t)65536 * 1024 * 2);         // GEMM2 out
    u16*  w1b  = (u16*)take((size_t)1024 * 512 * 2);
    u16*  wml  = (u16*)take((size_t)512 * 1024 * 2);
    u16*  ab   = (u16*)take((size_t)64 * 1024 * 1024 * 2);     // bf16 copy of (a + I)
    const bool useAb = (off <= ws_size);

    if (useAb) rowsum_kernel<true ><<<16384, 256, 0, stream>>>(a, dsc, ab);
    else       rowsum_kernel<false><<<16384, 256, 0, stream>>>(a, dsc, nullptr);
    xst_kernel<<<dim3(8, 16, 64), 256, 0, stream>>>(x, dsc, xst);
    cvt_weights<<<2048, 256, 0, stream>>>(W1, Wmu, Wlv, w1b, wml);

    if (useAb)
        gemm256<1><<<dim3(2, 4, 64), 512, 131072, stream>>>(
            ab, xst, 1024, 1024L * 1024, 512L * 1024,
            dsc, h, nullptr, nullptr, nullptr, nullptr);
    else
        gemm_f32a<<<dim3(4, 8, 64), 256, 0, stream>>>(a, xst, dsc, x, h);

    gemm256<2><<<dim3(4, 256, 1), 512, 131072, stream>>>(
        h, w1b, 512, 0, 0, nullptr, hid, b1, nullptr, nullptr, nullptr);

    gemm256<3><<<dim3(2, 256, 1), 512, 131072, stream>>>(
        hid, wml, 1024, 0, 0, nullptr, nullptr, bmu, blv,
        out, out + (size_t)65536 * 256);
}

// Round 4
// 760.802 us; speedup vs baseline: 1.1524x; 1.0095x over previous
//
#include <hip/hip_runtime.h>
#include <hip/hip_bf16.h>

typedef unsigned short u16;
typedef __attribute__((ext_vector_type(8))) short s16x8;
typedef __attribute__((ext_vector_type(4))) float f32x4;

// fp32 -> bf16 round-to-nearest-even
__device__ __forceinline__ u16 f2bf(float f) {
    union { float f; unsigned u; } c; c.f = f;
    unsigned r = c.u + 0x7fffu + ((c.u >> 16) & 1u);
    return (u16)(r >> 16);
}

// async global->LDS, 16 bytes/lane. LDS dest is wave-uniform base + lane*16.
__device__ __forceinline__ void gld_lds16(const u16* g, u16* l) {
    __builtin_amdgcn_global_load_lds(
        (const __attribute__((address_space(1))) void*)g,
        (__attribute__((address_space(3))) void*)l, 16, 0, 0);
}

// ---------------- prep: row-sums of a; a->bf16 with +I folded into the diagonal -----------------
template<bool CVT>
__global__ __launch_bounds__(256) void rowsum_kernel(const float* __restrict__ a,
                                                     float* __restrict__ dsc,
                                                     u16* __restrict__ ab) {
    const int wave = threadIdx.x >> 6, lane = threadIdx.x & 63;
    const long row = (long)blockIdx.x * 4 + wave;   // 65536 rows, each 1024 floats
    const int diag = (int)(row & 1023);             // column index of the +I element
    const float4* a4 = (const float4*)(a + row * 1024);
    float s = 0.f;
    #pragma unroll
    for (int i = 0; i < 4; ++i) {
        float4 v = a4[i * 64 + lane];
        s += v.x + v.y + v.z + v.w;                 // raw rowsum (deg adds +1 below)
        if (CVT) {
            const int c0 = (i * 64 + lane) * 4;
            float e[4] = {v.x, v.y, v.z, v.w};
            if (diag >= c0 && diag < c0 + 4) e[diag - c0] += 1.0f;  // fold +I into bf16 A
            union { u16 u[4]; uint2 w; } cv;
            cv.u[0] = f2bf(e[0]); cv.u[1] = f2bf(e[1]);
            cv.u[2] = f2bf(e[2]); cv.u[3] = f2bf(e[3]);
            *(uint2*)(ab + row * 1024 + c0) = cv.w;
        }
    }
    #pragma unroll
    for (int off = 32; off > 0; off >>= 1) s += __shfl_down(s, off, 64);
    if (lane == 0) dsc[row] = rsqrtf(s + 1.0f + 1e-8f);
}

// ---------------- prep: xst[b][n][j] = bf16(d_j * x[b][j][n])  (transpose so GEMM1 B is [N,K]) ----
__global__ __launch_bounds__(256) void xst_kernel(const float* __restrict__ x,
                                                  const float* __restrict__ dsc,
                                                  u16* __restrict__ xst) {
    __shared__ u16 ls[64][65];
    const int b  = blockIdx.z;
    const int n0 = blockIdx.x * 64;   // over IN_DIM=512
    const int j0 = blockIdx.y * 64;   // over N=1024
    const int t  = threadIdx.x;
    {
        int jj = t >> 4, nn = (t & 15) * 4;
        #pragma unroll
        for (int it = 0; it < 4; ++it, jj += 16) {
            float dj = dsc[b * 1024 + j0 + jj];
            float4 v = *(const float4*)(x + ((long)(b * 1024 + j0 + jj)) * 512 + n0 + nn);
            ls[jj][nn + 0] = f2bf(v.x * dj);
            ls[jj][nn + 1] = f2bf(v.y * dj);
            ls[jj][nn + 2] = f2bf(v.z * dj);
            ls[jj][nn + 3] = f2bf(v.w * dj);
        }
    }
    __syncthreads();
    {
        int nn = t >> 2;
        int jv = (t & 3) * 8;
        #pragma unroll
        for (int it = 0; it < 2; ++it, jv += 32) {
            union { u16 u[8]; uint4 w; } cv;
            #pragma unroll
            for (int u = 0; u < 8; ++u) cv.u[u] = ls[jv + u][nn];
            *(uint4*)(xst + ((long)b * 512 + n0 + nn) * 1024 + j0 + jv) = cv.w;
        }
    }
}

// ---------------- prep: weights -> bf16; W_mu/W_lv concatenated into [512][1024] -----------------
__global__ __launch_bounds__(256) void cvt_weights(const float* __restrict__ W1,
                                                   const float* __restrict__ Wmu,
                                                   const float* __restrict__ Wlv,
                                                   u16* __restrict__ w1b,
                                                   u16* __restrict__ wml) {
    int i = blockIdx.x * 256 + threadIdx.x;          // 524288 = 1024*512 = 512*1024
    w1b[i] = f2bf(W1[i]);
    wml[i] = f2bf(i < 262144 ? Wmu[i] : Wlv[i - 262144]);
}

// ================= 256x256-tile GEMM, 4-deep ring (prefetch distance 3), dynamic LDS ============
// C[m,n] = sum_k A[m,k]*Bt[n,k], bf16, BM=BN=256, BK=32, 8 waves (2Mx4N), per-wave 128x64 out.
// LDS 128KB dynamic: 4 ring slots x (A 16KB + B 16KB). Staging: global_load_lds width-16,
// linear LDS dest, source chunk pre-swizzled c ^= (row>>1)&3 (16B granules); ds_read applies the
// same XOR -> 2-way bank aliasing only (free, m136).
// Per K-tile (2 barriers, minimal set):
//   {STAGE t+3; 12x ds_read_b128; vmcnt(8); BAR1(publish t+1); prio1; 32 MFMA; prio0; BAR2(slot free)}
// BAR1 required: each wave stages 1/8 of the tile, publication needs all waves past their vmcnt.
// BAR2 required: leading wave's next STAGE overwrites slot t&3; trailing wave's ds_reads of tile t
// must be complete (they are, before its MFMA cluster ends, which precedes BAR2).
// vmcnt(8) => tile t+1 landed, t+2/t+3 in flight (distance-3 cover of ~900cy HBM latency).
template<int EPI>
__global__ __launch_bounds__(512, 2) void gemm256(
    const u16* __restrict__ A, const u16* __restrict__ Bt,
    int K, long aBStride, long bBStride,
    const float* __restrict__ dsc,
    u16* __restrict__ outb,
    const float* __restrict__ bias0, const float* __restrict__ bias1,
    float* __restrict__ outMu, float* __restrict__ outLv)
{
    extern __shared__ __align__(16) u16 smem[];   // 128KB: As 4x8192 u16, Bs 4x8192 u16
    u16* const Asl = smem;
    u16* const Bsl = smem + 4 * 8192;

    // --- XCD-aware bijective block swizzle (all launches have nwg % 8 == 0) ---
    const int gx = gridDim.x, gy = gridDim.y;
    const int nwg = gx * gy * gridDim.z;
    const int fid = (blockIdx.z * gy + blockIdx.y) * gx + blockIdx.x;
    int swz = fid;
    if (!(nwg & 7)) swz = (fid & 7) * (nwg >> 3) + (fid >> 3);
    const int bx  = swz % gx;
    const int tmp = swz / gx;
    const int by  = tmp % gy;
    const int bz  = tmp / gy;

    const u16* Ab = A + (long)bz * aBStride;
    const u16* Bb = Bt + (long)bz * bBStride;
    const int n0 = bx * 256, m0 = by * 256;
    const int T = (int)threadIdx.x;
    const int wid = T >> 6, lane = T & 63, quad = lane >> 4, tr = lane & 15;
    const int wm = (wid >> 2) * 128;      // wave row-block (2)
    const int wn = (wid & 3) * 64;        // wave col-block (4)
    const int NT = K >> 5;                // K-tiles of 32

    // staging: thread T -> row T/4 (0..127) per 128-row slot-half, 16B chunk T&3.
    // source chunk inverse-swizzled so LDS(r,c) = global(r, c ^ ((r>>1)&3)).
    const int sr   = T >> 2;
    const int scol = ((T & 3) ^ ((sr >> 1) & 3)) << 3;   // u16 units
    const u16* gA = Ab + (long)(m0 + sr) * K + scol;
    const u16* gB = Bb + (long)(n0 + sr) * K + scol;
    const long rowK = (long)128 * K;
    const int wofs = wid * 512;                          // wave-uniform LDS chunk (u16)

    f32x4 acc[8][4];
    #pragma unroll
    for (int i = 0; i < 8; ++i)
        #pragma unroll
        for (int j = 0; j < 4; ++j) acc[i][j] = (f32x4){0.f, 0.f, 0.f, 0.f};

    // read-side: global chunk 'quad' of row r lives at LDS chunk quad ^ ((r>>1)&3)
    const int rofs = (quad ^ ((tr >> 1) & 3)) << 3;      // u16 units
    const int rbA  = (wm + tr) * 32 + rofs;
    const int rbB  = (wn + tr) * 32 + rofs;

    #define STAGE(slot, t) do {                                         \
        const u16* ga_ = gA + (long)(t) * 32;                           \
        const u16* gb_ = gB + (long)(t) * 32;                           \
        u16* la_ = Asl + (slot) * 8192 + wofs;                          \
        u16* lb_ = Bsl + (slot) * 8192 + wofs;                          \
        gld_lds16(ga_, la_); gld_lds16(ga_ + rowK, la_ + 4096);         \
        gld_lds16(gb_, lb_); gld_lds16(gb_ + rowK, lb_ + 4096);         \
    } while (0)

    // prologue: stage tiles 0,1,2 (12 loads); wait oldest 4 (tile 0); 8 stay in flight
    STAGE(0, 0); STAGE(1, 1); STAGE(2, 2);
    asm volatile("s_waitcnt vmcnt(8)" ::: "memory");
    __builtin_amdgcn_s_barrier();
    __builtin_amdgcn_sched_barrier(0);

    for (int t = 0; t < NT; ++t) {
        const u16* rdA = Asl + (t & 3) * 8192;
        const u16* rdB = Bsl + (t & 3) * 8192;
        s16x8 af0[4], bfv[4], af1[4];
        // ---- issue next-tile staging first (slot hazard cleared by iter t-1's BAR2) ----
        if (t + 3 < NT) STAGE((t + 3) & 3, t + 3);
        // ---- all 12 fragment reads for tile t (published by iter t-1's BAR1) ----
        #pragma unroll
        for (int i = 0; i < 4; ++i) af0[i] = *(const s16x8*)&rdA[rbA + i * 512];
        #pragma unroll
        for (int i = 0; i < 4; ++i) bfv[i] = *(const s16x8*)&rdB[rbB + i * 512];
        #pragma unroll
        for (int i = 0; i < 4; ++i) af1[i] = *(const s16x8*)&rdA[rbA + 2048 + i * 512];
        // ---- counted vmcnt: tile t+1 landed (for this wave); never 0 in steady state ----
        if (t + 3 < NT) {
            asm volatile("s_waitcnt vmcnt(8)" ::: "memory");   // t+1 landed; t+2,t+3 in flight
        } else if (t + 2 < NT) {
            asm volatile("s_waitcnt vmcnt(4)" ::: "memory");   // t+1 landed; t+2 in flight
        } else if (t + 1 < NT) {
            asm volatile("s_waitcnt vmcnt(0)" ::: "memory");   // tail drain
        }
        __builtin_amdgcn_s_barrier();                          // BAR1: tile t+1 published
        __builtin_amdgcn_sched_barrier(0);
        // ---- single 32-MFMA cluster (compiler inserts counted lgkm waits for frags) ----
        __builtin_amdgcn_s_setprio(1);
        #pragma unroll
        for (int mi = 0; mi < 4; ++mi)
            #pragma unroll
            for (int ni = 0; ni < 4; ++ni)
                acc[mi][ni] = __builtin_amdgcn_mfma_f32_16x16x32_bf16(af0[mi], bfv[ni], acc[mi][ni], 0, 0, 0);
        #pragma unroll
        for (int mi = 0; mi < 4; ++mi)
            #pragma unroll
            for (int ni = 0; ni < 4; ++ni)
                acc[mi + 4][ni] = __builtin_amdgcn_mfma_f32_16x16x32_bf16(af1[mi], bfv[ni], acc[mi + 4][ni], 0, 0, 0);
        __builtin_amdgcn_s_setprio(0);
        __builtin_amdgcn_s_barrier();                          // BAR2: slot t&3 free for reuse
        __builtin_amdgcn_sched_barrier(0);
    }
    #undef STAGE

    // ---- epilogue: C/D layout col=lane&15, row=quad*4+reg (m89-verified) ----
    if constexpr (EPI == 1) {
        #pragma unroll
        for (int mi = 0; mi < 8; ++mi) {
            const int gmB = m0 + wm + mi * 16 + quad * 4;
            #pragma unroll
            for (int r = 0; r < 4; ++r) {
                const long row = (long)bz * 1024 + gmB + r;
                const float d = dsc[row];
                #pragma unroll
                for (int ni = 0; ni < 4; ++ni) {
                    const int gn = n0 + wn + ni * 16 + tr;
                    outb[row * 512 + gn] = f2bf(d * acc[mi][ni][r]);
                }
            }
        }
    } else if constexpr (EPI == 2) {
        float bb[4];
        #pragma unroll
        for (int ni = 0; ni < 4; ++ni) bb[ni] = bias0[n0 + wn + ni * 16 + tr];
        #pragma unroll
        for (int mi = 0; mi < 8; ++mi) {
            const long gmB = m0 + wm + mi * 16 + quad * 4;
            #pragma unroll
            for (int ni = 0; ni < 4; ++ni) {
                const int gn = n0 + wn + ni * 16 + tr;
                #pragma unroll
                for (int r = 0; r < 4; ++r) {
                    float hv = acc[mi][ni][r] + bb[ni];
                    outb[(gmB + r) * 1024 + gn] = f2bf(hv > 0.f ? hv : 0.f);
                }
            }
        }
    } else {
        // n0 in {0,256}: entire block is mu or lv
        float* op       = (n0 == 0) ? outMu : outLv;
        const float* bp = (n0 == 0) ? bias0 : bias1;
        float bb[4];
        #pragma unroll
        for (int ni = 0; ni < 4; ++ni) bb[ni] = bp[wn + ni * 16 + tr];
        #pragma unroll
        for (int mi = 0; mi < 8; ++mi) {
            const long gmB = m0 + wm + mi * 16 + quad * 4;
            #pragma unroll
            for (int ni = 0; ni < 4; ++ni) {
                const int cn = wn + ni * 16 + tr;
                #pragma unroll
                for (int r = 0; r < 4; ++r)
                    op[(gmB + r) * 256 + cn] = acc[mi][ni][r] + bb[ni];
            }
        }
    }
}

// ---------------- fallback GEMM1 (fp32 A inline-converted) if ws can't hold bf16 a ---------------
__global__ __launch_bounds__(256) void gemm_f32a(
    const float* __restrict__ A, const u16* __restrict__ Bt,
    const float* __restrict__ dsc, const float* __restrict__ xin,
    u16* __restrict__ outb)
{
    __shared__ __align__(16) u16 As[128 * 40];
    __shared__ __align__(16) u16 Bs[128 * 40];
    const int bz = blockIdx.z;
    const float* Ab = A + (long)bz * 1024 * 1024;
    const u16* Bb = Bt + (long)bz * 512 * 1024;
    const int n0 = blockIdx.x * 128, m0 = blockIdx.y * 128;
    const int t = threadIdx.x;
    const int wave = t >> 6, lane = t & 63, quad = lane >> 4, tr = lane & 15;
    const int wm = (wave >> 1) * 64, wn = (wave & 1) * 64;
    const int K = 1024;

    f32x4 acc[4][4];
    #pragma unroll
    for (int i = 0; i < 4; ++i)
        #pragma unroll
        for (int j = 0; j < 4; ++j) acc[i][j] = (f32x4){0.f, 0.f, 0.f, 0.f};

    const int mm = t >> 2, kk = (t & 3) * 8;
    for (int k0 = 0; k0 < K; k0 += 32) {
        #pragma unroll
        for (int it = 0; it < 2; ++it) {
            const int r = mm + it * 64;
            const float4* p = (const float4*)(Ab + (long)(m0 + r) * K + k0 + kk);
            float4 v0 = p[0], v1 = p[1];
            union { u16 u[8]; uint4 w; } cv;
            cv.u[0]=f2bf(v0.x); cv.u[1]=f2bf(v0.y); cv.u[2]=f2bf(v0.z); cv.u[3]=f2bf(v0.w);
            cv.u[4]=f2bf(v1.x); cv.u[5]=f2bf(v1.y); cv.u[6]=f2bf(v1.z); cv.u[7]=f2bf(v1.w);
            *(uint4*)&As[r * 40 + kk] = cv.w;
            uint4 v = *(const uint4*)(Bb + (long)(n0 + r) * K + k0 + kk);
            *(uint4*)&Bs[r * 40 + kk] = v;
        }
        __syncthreads();
        s16x8 af[4], bfv[4];
        #pragma unroll
        for (int mi = 0; mi < 4; ++mi)
            af[mi] = *(const s16x8*)&As[(wm + mi * 16 + tr) * 40 + quad * 8];
        #pragma unroll
        for (int ni = 0; ni < 4; ++ni)
            bfv[ni] = *(const s16x8*)&Bs[(wn + ni * 16 + tr) * 40 + quad * 8];
        #pragma unroll
        for (int mi = 0; mi < 4; ++mi)
            #pragma unroll
            for (int ni = 0; ni < 4; ++ni)
                acc[mi][ni] = __builtin_amdgcn_mfma_f32_16x16x32_bf16(af[mi], bfv[ni], acc[mi][ni], 0, 0, 0);
        __syncthreads();
    }
    #pragma unroll
    for (int mi = 0; mi < 4; ++mi)
        #pragma unroll
        for (int ni = 0; ni < 4; ++ni) {
            const int gn = n0 + wn + ni * 16 + tr;
            #pragma unroll
            for (int r = 0; r < 4; ++r) {
                const int gm = m0 + wm + mi * 16 + quad * 4 + r;
                long row = (long)bz * 1024 + gm;
                float di = dsc[row];
                outb[row * 512 + gn] = f2bf(di * (acc[mi][ni][r] + di * xin[row * 512 + gn]));
            }
        }
}

extern "C" void kernel_launch(void* const* d_in, const int* in_sizes, int n_in,
                              void* d_out, int out_size, void* d_ws, size_t ws_size,
                              hipStream_t stream) {
    const float* x   = (const float*)d_in[0];   // [64,1024,512]
    const float* a   = (const float*)d_in[1];   // [64,1024,1024]
    const float* W1  = (const float*)d_in[2];   // [1024,512]
    const float* b1  = (const float*)d_in[3];   // [1024]
    const float* Wmu = (const float*)d_in[4];   // [256,1024]
    const float* bmu = (const float*)d_in[5];   // [256]
    const float* Wlv = (const float*)d_in[6];   // [256,1024]
    const float* blv = (const float*)d_in[7];   // [256]
    float* out = (float*)d_out;                 // mu [64,1024,256] then logvar [64,1024,256]

    // one-time: allow 128KB dynamic LDS on the gemm kernels (host-side, capture-safe; ignore rc)
    static bool attrDone = false;
    if (!attrDone) {
        (void)hipFuncSetAttribute((const void*)gemm256<1>, hipFuncAttributeMaxDynamicSharedMemorySize, 131072);
        (void)hipFuncSetAttribute((const void*)gemm256<2>, hipFuncAttributeMaxDynamicSharedMemorySize, 131072);
        (void)hipFuncSetAttribute((const void*)gemm256<3>, hipFuncAttributeMaxDynamicSharedMemorySize, 131072);
        attrDone = true;
    }

    char* base = (char*)d_ws;
    size_t off = 0;
    auto take = [&](size_t bytes) { char* p = base + off; off += (bytes + 255) & ~(size_t)255; return p; };
    float* dsc = (float*)take((size_t)65536 * 4);              // D^-1/2 per (b,i)
    u16*  xst  = (u16*)take((size_t)64 * 512 * 1024 * 2);      // [b][n][j] bf16
    u16*  h    = (u16*)take((size_t)65536 * 512 * 2);          // GEMM1 out
    u16*  hid  = (u16*)take((size_t)65536 * 1024 * 2);         // GEMM2 out
    u16*  w1b  = (u16*)take((size_t)1024 * 512 * 2);
    u16*  wml  = (u16*)take((size_t)512 * 1024 * 2);
    u16*  ab   = (u16*)take((size_t)64 * 1024 * 1024 * 2);     // bf16 copy of (a + I)
    const bool useAb = (off <= ws_size);

    if (useAb) rowsum_kernel<true ><<<16384, 256, 0, stream>>>(a, dsc, ab);
    else       rowsum_kernel<false><<<16384, 256, 0, stream>>>(a, dsc, nullptr);
    xst_kernel<<<dim3(8, 16, 64), 256, 0, stream>>>(x, dsc, xst);
    cvt_weights<<<2048, 256, 0, stream>>>(W1, Wmu, Wlv, w1b, wml);

    if (useAb)
        gemm256<1><<<dim3(2, 4, 64), 512, 131072, stream>>>(
            ab, xst, 1024, 1024L * 1024, 512L * 1024,
            dsc, h, nullptr, nullptr, nullptr, nullptr);
    else
        gemm_f32a<<<dim3(4, 8, 64), 256, 0, stream>>>(a, xst, dsc, x, h);

    gemm256<2><<<dim3(4, 256, 1), 512, 131072, stream>>>(
        h, w1b, 512, 0, 0, nullptr, hid, b1, nullptr, nullptr, nullptr);

    gemm256<3><<<dim3(2, 256, 1), 512, 131072, stream>>>(
        hid, wml, 1024, 0, 0, nullptr, nullptr, bmu, blv,
        out, out + (size_t)65536 * 256);
}